// Round 1
// baseline (11075.205 us; speedup 1.0000x reference)
//
#include <hip/hip_runtime.h>
#include <hip/hip_bf16.h>

// Problem constants (from reference): N=100000, IN=512, OUT=256, E=3200000
#define IN_DIM  512
#define OUT_DIM 256

using bf16x8 = __attribute__((ext_vector_type(8))) __bf16;
using f32x4  = __attribute__((ext_vector_type(4))) float;

// --- Kernel 1: W[512][256] f32 -> Wt[256][512] bf16 (transposed, for B-frag rows) ---
__global__ void convert_weight(const float* __restrict__ W, __bf16* __restrict__ Wt) {
    int idx = blockIdx.x * blockDim.x + threadIdx.x;   // 0..131071
    int n = idx >> 9;          // out col
    int k = idx & 511;         // in dim
    Wt[idx] = (__bf16)W[k * OUT_DIM + n];
}

// --- Kernel 2: support = tanh(x @ W), bf16 MFMA, one wave per 16 rows x 256 cols ---
__launch_bounds__(256)
__global__ void gemm_tanh(const float* __restrict__ x, const __bf16* __restrict__ Wt,
                          float* __restrict__ support, const int* __restrict__ active,
                          int N) {
    const int wave = threadIdx.x >> 6;
    const int lane = threadIdx.x & 63;
    const int m    = lane & 15;     // A row / B col / C col
    const int quad = lane >> 4;     // k-block selector, C row-block
    const int r0   = (blockIdx.x * 4 + wave) * 16;
    if (r0 >= N) return;            // N % 16 == 0, so whole-tile guard suffices

    const float* xrow = x + (size_t)(r0 + m) * IN_DIM;

    f32x4 acc[16];
#pragma unroll
    for (int t = 0; t < 16; ++t) acc[t] = (f32x4)0.0f;

    for (int k0 = 0; k0 < IN_DIM; k0 += 32) {
        // A fragment: A[m][k0 + quad*8 + j], j=0..7 -> two float4 loads, cvt to bf16
        const float4* ap = (const float4*)(xrow + k0 + quad * 8);
        float4 a0 = ap[0];
        float4 a1 = ap[1];
        bf16x8 af;
        af[0] = (__bf16)a0.x; af[1] = (__bf16)a0.y; af[2] = (__bf16)a0.z; af[3] = (__bf16)a0.w;
        af[4] = (__bf16)a1.x; af[5] = (__bf16)a1.y; af[6] = (__bf16)a1.z; af[7] = (__bf16)a1.w;
#pragma unroll
        for (int t = 0; t < 16; ++t) {
            // B fragment: B[k][n] with n = t*16+m, k = k0 + quad*8 + j  (Wt is [n][k])
            bf16x8 bf = *(const bf16x8*)(Wt + (size_t)(t * 16 + m) * IN_DIM + k0 + quad * 8);
            acc[t] = __builtin_amdgcn_mfma_f32_16x16x32_bf16(af, bf, acc[t], 0, 0, 0);
        }
    }

    const int act = active[0];      // nonzero for 1 under int32/int64/float encodings
    const int row_base = r0 + quad * 4;
#pragma unroll
    for (int t = 0; t < 16; ++t) {
#pragma unroll
        for (int r = 0; r < 4; ++r) {
            float v = acc[t][r];
            if (act) v = tanhf(v);
            support[(size_t)(row_base + r) * OUT_DIM + t * 16 + m] = v;
        }
    }
}

// --- Kernel 3: out[rows[e]] += vals[e] * support[cols[e]]  (wave per edge) ---
__launch_bounds__(256)
__global__ void spmm_scatter(const float* __restrict__ support,
                             const int* __restrict__ rows,
                             const int* __restrict__ cols,
                             const float* __restrict__ vals,
                             float* __restrict__ out, int E) {
    int e    = (int)((blockIdx.x * 256u + threadIdx.x) >> 6);
    int lane = threadIdx.x & 63;
    if (e >= E) return;
    int   r = rows[e];
    int   c = cols[e];
    float v = vals[e];
    float4 s = *((const float4*)(support + (size_t)c * OUT_DIM) + lane);
    float* dst = out + (size_t)r * OUT_DIM + lane * 4;
    atomicAdd(dst + 0, s.x * v);
    atomicAdd(dst + 1, s.y * v);
    atomicAdd(dst + 2, s.z * v);
    atomicAdd(dst + 3, s.w * v);
}

extern "C" void kernel_launch(void* const* d_in, const int* in_sizes, int n_in,
                              void* d_out, int out_size, void* d_ws, size_t ws_size,
                              hipStream_t stream) {
    const float* x     = (const float*)d_in[0];
    const float* W     = (const float*)d_in[1];
    const int*   erows = (const int*)d_in[2];
    const int*   ecols = (const int*)d_in[3];
    const float* evals = (const float*)d_in[4];
    const int*   activ = (const int*)d_in[5];
    float*       out   = (float*)d_out;

    const int N = in_sizes[0] / IN_DIM;   // 100000
    const int E = in_sizes[2];            // 3200000

    // Workspace layout: support f32 [N][256] | Wt bf16 [256][512]
    float*  support = (float*)d_ws;
    __bf16* Wt      = (__bf16*)((char*)d_ws + (size_t)N * OUT_DIM * sizeof(float));

    convert_weight<<<(IN_DIM * OUT_DIM) / 256, 256, 0, stream>>>(W, Wt);

    const int row_tiles   = (N + 15) / 16;        // 6250
    const int gemm_blocks = (row_tiles + 3) / 4;  // 1563
    gemm_tanh<<<gemm_blocks, 256, 0, stream>>>(x, Wt, support, activ, N);

    hipMemsetAsync(d_out, 0, (size_t)out_size * sizeof(float), stream);

    const int scat_blocks = (E + 3) / 4;          // wave per edge, 4 waves/block
    spmm_scatter<<<scat_blocks, 256, 0, stream>>>(support, erows, ecols, evals, out, E);
}

// Round 2
// 1343.906 us; speedup vs baseline: 8.2411x; 8.2411x over previous
//
#include <hip/hip_runtime.h>
#include <hip/hip_bf16.h>

// Problem constants (from reference): N=100000, IN=512, OUT=256, E=3200000
#define IN_DIM  512
#define OUT_DIM 256

using bf16x8 = __attribute__((ext_vector_type(8))) __bf16;
using f32x4  = __attribute__((ext_vector_type(4))) float;

// --- Kernel 1: W[512][256] f32 -> Wt[256][512] bf16 (transposed, for B-frag rows) ---
__global__ void convert_weight(const float* __restrict__ W, __bf16* __restrict__ Wt) {
    int idx = blockIdx.x * blockDim.x + threadIdx.x;   // 0..131071
    int n = idx >> 9;          // out col
    int k = idx & 511;         // in dim
    Wt[idx] = (__bf16)W[k * OUT_DIM + n];
}

// --- Kernel 2: support = tanh(x @ W), bf16 MFMA, one wave per 16 rows x 256 cols ---
__launch_bounds__(256)
__global__ void gemm_tanh(const float* __restrict__ x, const __bf16* __restrict__ Wt,
                          float* __restrict__ support, const int* __restrict__ active,
                          int N) {
    const int wave = threadIdx.x >> 6;
    const int lane = threadIdx.x & 63;
    const int m    = lane & 15;     // A row / B col / C col
    const int quad = lane >> 4;     // k-block selector, C row-block
    const int r0   = (blockIdx.x * 4 + wave) * 16;
    if (r0 >= N) return;            // N % 16 == 0, so whole-tile guard suffices

    const float* xrow = x + (size_t)(r0 + m) * IN_DIM;

    f32x4 acc[16];
#pragma unroll
    for (int t = 0; t < 16; ++t) acc[t] = (f32x4)0.0f;

    for (int k0 = 0; k0 < IN_DIM; k0 += 32) {
        // A fragment: A[m][k0 + quad*8 + j], j=0..7 -> two float4 loads, cvt to bf16
        const float4* ap = (const float4*)(xrow + k0 + quad * 8);
        float4 a0 = ap[0];
        float4 a1 = ap[1];
        bf16x8 af;
        af[0] = (__bf16)a0.x; af[1] = (__bf16)a0.y; af[2] = (__bf16)a0.z; af[3] = (__bf16)a0.w;
        af[4] = (__bf16)a1.x; af[5] = (__bf16)a1.y; af[6] = (__bf16)a1.z; af[7] = (__bf16)a1.w;
#pragma unroll
        for (int t = 0; t < 16; ++t) {
            // B fragment: B[k][n] with n = t*16+m, k = k0 + quad*8 + j  (Wt is [n][k])
            bf16x8 bf = *(const bf16x8*)(Wt + (size_t)(t * 16 + m) * IN_DIM + k0 + quad * 8);
            acc[t] = __builtin_amdgcn_mfma_f32_16x16x32_bf16(af, bf, acc[t], 0, 0, 0);
        }
    }

    const int act = active[0];
    const int row_base = r0 + quad * 4;
#pragma unroll
    for (int t = 0; t < 16; ++t) {
#pragma unroll
        for (int r = 0; r < 4; ++r) {
            float v = acc[t][r];
            if (act) v = tanhf(v);
            support[(size_t)(row_base + r) * OUT_DIM + t * 16 + m] = v;
        }
    }
}

// --- Kernel 3a: histogram of destination rows ---
__launch_bounds__(256)
__global__ void edge_hist(const int* __restrict__ rows, int* __restrict__ counts, int E) {
    int e = blockIdx.x * 256 + threadIdx.x;
    if (e < E) atomicAdd(&counts[rows[e]], 1);
}

// --- Kernel 3b: allocate contiguous segment bases (wave prefix-sum + 1 atomic/wave) ---
__launch_bounds__(256)
__global__ void alloc_bases(const int* __restrict__ counts, int* __restrict__ base,
                            int* __restrict__ cursor, int* __restrict__ gcursor, int N) {
    int i = blockIdx.x * 256 + threadIdx.x;
    int lane = threadIdx.x & 63;
    int c = (i < N) ? counts[i] : 0;
    // inclusive wave prefix sum
    int pref = c;
#pragma unroll
    for (int d = 1; d < 64; d <<= 1) {
        int up = __shfl_up(pref, d, 64);
        if (lane >= d) pref += up;
    }
    int total = __shfl(pref, 63, 64);
    int waveBase = 0;
    if (lane == 63) waveBase = atomicAdd(gcursor, total);
    waveBase = __shfl(waveBase, 63, 64);
    int b = waveBase + pref - c;   // exclusive prefix
    if (i < N) { base[i] = b; cursor[i] = b; }
}

// --- Kernel 3c: scatter (col, val) into row-contiguous segments ---
__launch_bounds__(256)
__global__ void edge_scatter(const int* __restrict__ rows, const int* __restrict__ cols,
                             const float* __restrict__ vals, int* __restrict__ cursor,
                             int2* __restrict__ sorted, int E) {
    int e = blockIdx.x * 256 + threadIdx.x;
    if (e >= E) return;
    int r = rows[e];
    int pos = atomicAdd(&cursor[r], 1);
    int2 ce;
    ce.x = cols[e];
    ce.y = __float_as_int(vals[e]);
    sorted[pos] = ce;
}

// --- Kernel 3d: one wave per output row; register-accumulate its edge segment ---
__launch_bounds__(256)
__global__ void row_accumulate(const float* __restrict__ support,
                               const int* __restrict__ base,
                               const int* __restrict__ counts,
                               const int2* __restrict__ sorted,
                               float* __restrict__ out, int N) {
    int w    = (int)((blockIdx.x * 256u + threadIdx.x) >> 6);  // row id
    int lane = threadIdx.x & 63;
    if (w >= N) return;
    int e   = base[w];
    int end = e + counts[w];

    f32x4 acc = (f32x4)0.0f;
    // 2-wide unroll: two independent gathers in flight per wave
    for (; e + 2 <= end; e += 2) {
        int2 ce0 = sorted[e];
        int2 ce1 = sorted[e + 1];
        float4 s0 = *((const float4*)(support + (size_t)ce0.x * OUT_DIM) + lane);
        float4 s1 = *((const float4*)(support + (size_t)ce1.x * OUT_DIM) + lane);
        float v0 = __int_as_float(ce0.y);
        float v1 = __int_as_float(ce1.y);
        acc[0] += v0 * s0.x; acc[1] += v0 * s0.y; acc[2] += v0 * s0.z; acc[3] += v0 * s0.w;
        acc[0] += v1 * s1.x; acc[1] += v1 * s1.y; acc[2] += v1 * s1.z; acc[3] += v1 * s1.w;
    }
    if (e < end) {
        int2 ce = sorted[e];
        float4 s = *((const float4*)(support + (size_t)ce.x * OUT_DIM) + lane);
        float v = __int_as_float(ce.y);
        acc[0] += v * s.x; acc[1] += v * s.y; acc[2] += v * s.z; acc[3] += v * s.w;
    }
    float4 o;
    o.x = acc[0]; o.y = acc[1]; o.z = acc[2]; o.w = acc[3];
    *((float4*)(out + (size_t)w * OUT_DIM) + lane) = o;
}

extern "C" void kernel_launch(void* const* d_in, const int* in_sizes, int n_in,
                              void* d_out, int out_size, void* d_ws, size_t ws_size,
                              hipStream_t stream) {
    const float* x     = (const float*)d_in[0];
    const float* W     = (const float*)d_in[1];
    const int*   erows = (const int*)d_in[2];
    const int*   ecols = (const int*)d_in[3];
    const float* evals = (const float*)d_in[4];
    const int*   activ = (const int*)d_in[5];
    float*       out   = (float*)d_out;

    const int N = in_sizes[0] / IN_DIM;   // 100000
    const int E = in_sizes[2];            // 3200000

    // Workspace layout (16B-aligned chunks):
    //   support f32 [N][256]            : 102.4 MB
    //   Wt bf16 [256][512]              : 0.25 MB
    //   counts int [N], base int [N], cursor int [N], gcursor int[4]
    //   sorted int2 [E]                 : 25.6 MB
    char* p = (char*)d_ws;
    float*  support = (float*)p;            p += (size_t)N * OUT_DIM * sizeof(float);
    __bf16* Wt      = (__bf16*)p;           p += (size_t)IN_DIM * OUT_DIM * sizeof(__bf16);
    int*    counts  = (int*)p;              p += (size_t)N * sizeof(int);
    int*    base    = (int*)p;              p += (size_t)N * sizeof(int);
    int*    cursor  = (int*)p;              p += (size_t)N * sizeof(int);
    int*    gcursor = (int*)p;              p += 16;
    int2*   sorted  = (int2*)p;             p += (size_t)E * sizeof(int2);

    convert_weight<<<(IN_DIM * OUT_DIM) / 256, 256, 0, stream>>>(W, Wt);

    const int row_tiles   = (N + 15) / 16;
    const int gemm_blocks = (row_tiles + 3) / 4;
    gemm_tanh<<<gemm_blocks, 256, 0, stream>>>(x, Wt, support, activ, N);

    // zero counts + gcursor (contiguous region)
    hipMemsetAsync(counts, 0, (size_t)N * sizeof(int), stream);
    hipMemsetAsync(gcursor, 0, 16, stream);

    const int eblocks = (E + 255) / 256;
    edge_hist<<<eblocks, 256, 0, stream>>>(erows, counts, E);
    alloc_bases<<<(N + 255) / 256, 256, 0, stream>>>(counts, base, cursor, gcursor, N);
    edge_scatter<<<eblocks, 256, 0, stream>>>(erows, ecols, evals, cursor, sorted, E);

    const int acc_blocks = (N + 3) / 4;    // wave per row, 4 waves/block
    row_accumulate<<<acc_blocks, 256, 0, stream>>>(support, base, counts, sorted, out, N);
}

// Round 3
// 1158.644 us; speedup vs baseline: 9.5588x; 1.1599x over previous
//
#include <hip/hip_runtime.h>
#include <hip/hip_bf16.h>

// Problem constants (from reference): N=100000, IN=512, OUT=256, E=3200000
#define IN_DIM  512
#define OUT_DIM 256

using bf16x8 = __attribute__((ext_vector_type(8))) __bf16;
using f32x4  = __attribute__((ext_vector_type(4))) float;

// --- Kernel 1: W[512][256] f32 -> Wt[256][512] bf16 (transposed, for B-frag rows) ---
__global__ void convert_weight(const float* __restrict__ W, __bf16* __restrict__ Wt) {
    int idx = blockIdx.x * blockDim.x + threadIdx.x;   // 0..131071
    int n = idx >> 9;          // out col
    int k = idx & 511;         // in dim
    Wt[idx] = (__bf16)W[k * OUT_DIM + n];
}

// --- Kernel 2: support = tanh(x @ W) in bf16, MFMA, one wave per 16 rows x 256 cols ---
__launch_bounds__(256)
__global__ void gemm_tanh(const float* __restrict__ x, const __bf16* __restrict__ Wt,
                          __hip_bfloat16* __restrict__ support, const int* __restrict__ active,
                          int N) {
    const int wave = threadIdx.x >> 6;
    const int lane = threadIdx.x & 63;
    const int m    = lane & 15;     // A row / B col / C col
    const int quad = lane >> 4;     // k-block selector, C row-block
    const int r0   = (blockIdx.x * 4 + wave) * 16;
    if (r0 >= N) return;            // N % 16 == 0

    const float* xrow = x + (size_t)(r0 + m) * IN_DIM;

    f32x4 acc[16];
#pragma unroll
    for (int t = 0; t < 16; ++t) acc[t] = (f32x4)0.0f;

    for (int k0 = 0; k0 < IN_DIM; k0 += 32) {
        const float4* ap = (const float4*)(xrow + k0 + quad * 8);
        float4 a0 = ap[0];
        float4 a1 = ap[1];
        bf16x8 af;
        af[0] = (__bf16)a0.x; af[1] = (__bf16)a0.y; af[2] = (__bf16)a0.z; af[3] = (__bf16)a0.w;
        af[4] = (__bf16)a1.x; af[5] = (__bf16)a1.y; af[6] = (__bf16)a1.z; af[7] = (__bf16)a1.w;
#pragma unroll
        for (int t = 0; t < 16; ++t) {
            bf16x8 bf = *(const bf16x8*)(Wt + (size_t)(t * 16 + m) * IN_DIM + k0 + quad * 8);
            acc[t] = __builtin_amdgcn_mfma_f32_16x16x32_bf16(af, bf, acc[t], 0, 0, 0);
        }
    }

    const int act = active[0];
    const int row_base = r0 + quad * 4;
#pragma unroll
    for (int t = 0; t < 16; ++t) {
#pragma unroll
        for (int r = 0; r < 4; ++r) {
            float v = acc[t][r];
            if (act) v = tanhf(v);
            support[(size_t)(row_base + r) * OUT_DIM + t * 16 + m] = __float2bfloat16(v);
        }
    }
}

// --- Kernel 3a: histogram of destination rows ---
__launch_bounds__(256)
__global__ void edge_hist(const int* __restrict__ rows, int* __restrict__ counts, int E) {
    int e = blockIdx.x * 256 + threadIdx.x;
    if (e < E) atomicAdd(&counts[rows[e]], 1);
}

// --- Kernel 3b: allocate contiguous segment bases (wave prefix-sum + 1 atomic/wave) ---
__launch_bounds__(256)
__global__ void alloc_bases(const int* __restrict__ counts, int* __restrict__ base,
                            int* __restrict__ cursor, int* __restrict__ gcursor, int N) {
    int i = blockIdx.x * 256 + threadIdx.x;
    int lane = threadIdx.x & 63;
    int c = (i < N) ? counts[i] : 0;
    int pref = c;
#pragma unroll
    for (int d = 1; d < 64; d <<= 1) {
        int up = __shfl_up(pref, d, 64);
        if (lane >= d) pref += up;
    }
    int total = __shfl(pref, 63, 64);
    int waveBase = 0;
    if (lane == 63) waveBase = atomicAdd(gcursor, total);
    waveBase = __shfl(waveBase, 63, 64);
    int b = waveBase + pref - c;
    if (i < N) { base[i] = b; cursor[i] = b; }
}

// --- Kernel 3c: scatter (col, val) into row-contiguous segments (nt stores) ---
__launch_bounds__(256)
__global__ void edge_scatter(const int* __restrict__ rows, const int* __restrict__ cols,
                             const float* __restrict__ vals, int* __restrict__ cursor,
                             unsigned long long* __restrict__ sorted, int E) {
    int e = blockIdx.x * 256 + threadIdx.x;
    if (e >= E) return;
    int r = rows[e];
    int pos = atomicAdd(&cursor[r], 1);
    unsigned long long packed = (unsigned int)cols[e] |
        ((unsigned long long)(unsigned int)__float_as_int(vals[e]) << 32);
    __builtin_nontemporal_store(packed, &sorted[pos]);
}

// --- Kernel 3d: one wave per output row; register-accumulate its edge segment ---
__launch_bounds__(256)
__global__ void row_accumulate(const unsigned short* __restrict__ support,
                               const int* __restrict__ base,
                               const int* __restrict__ counts,
                               const unsigned long long* __restrict__ sorted,
                               float* __restrict__ out, int N) {
    int w    = (int)((blockIdx.x * 256u + threadIdx.x) >> 6);  // row id
    int lane = threadIdx.x & 63;
    if (w >= N) return;
    int e   = base[w];
    int end = e + counts[w];

    float a0 = 0.f, a1 = 0.f, a2 = 0.f, a3 = 0.f;

    // 4-wide unroll: four independent gathers in flight per wave
    for (; e + 4 <= end; e += 4) {
        unsigned long long p0 = __builtin_nontemporal_load(&sorted[e]);
        unsigned long long p1 = __builtin_nontemporal_load(&sorted[e + 1]);
        unsigned long long p2 = __builtin_nontemporal_load(&sorted[e + 2]);
        unsigned long long p3 = __builtin_nontemporal_load(&sorted[e + 3]);
#pragma unroll
        for (int j = 0; j < 4; ++j) {
            unsigned long long p = (j == 0) ? p0 : (j == 1) ? p1 : (j == 2) ? p2 : p3;
            int   c = (int)(unsigned int)p;
            float v = __int_as_float((int)(p >> 32));
            uint2 u = *((const uint2*)(support + (size_t)c * OUT_DIM) + lane);
            a0 = fmaf(v, __uint_as_float(u.x << 16),          a0);
            a1 = fmaf(v, __uint_as_float(u.x & 0xffff0000u),  a1);
            a2 = fmaf(v, __uint_as_float(u.y << 16),          a2);
            a3 = fmaf(v, __uint_as_float(u.y & 0xffff0000u),  a3);
        }
    }
    for (; e < end; ++e) {
        unsigned long long p = __builtin_nontemporal_load(&sorted[e]);
        int   c = (int)(unsigned int)p;
        float v = __int_as_float((int)(p >> 32));
        uint2 u = *((const uint2*)(support + (size_t)c * OUT_DIM) + lane);
        a0 = fmaf(v, __uint_as_float(u.x << 16),          a0);
        a1 = fmaf(v, __uint_as_float(u.x & 0xffff0000u),  a1);
        a2 = fmaf(v, __uint_as_float(u.y << 16),          a2);
        a3 = fmaf(v, __uint_as_float(u.y & 0xffff0000u),  a3);
    }
    float4 o;
    o.x = a0; o.y = a1; o.z = a2; o.w = a3;
    *((float4*)(out + (size_t)w * OUT_DIM) + lane) = o;
}

extern "C" void kernel_launch(void* const* d_in, const int* in_sizes, int n_in,
                              void* d_out, int out_size, void* d_ws, size_t ws_size,
                              hipStream_t stream) {
    const float* x     = (const float*)d_in[0];
    const float* W     = (const float*)d_in[1];
    const int*   erows = (const int*)d_in[2];
    const int*   ecols = (const int*)d_in[3];
    const float* evals = (const float*)d_in[4];
    const int*   activ = (const int*)d_in[5];
    float*       out   = (float*)d_out;

    const int N = in_sizes[0] / IN_DIM;   // 100000
    const int E = in_sizes[2];            // 3200000

    // Workspace layout (16B-aligned chunks):
    //   support bf16 [N][256]           : 51.2 MB
    //   Wt bf16 [256][512]              : 0.25 MB
    //   counts/base/cursor int [N], gcursor int[4]
    //   sorted u64 [E]                  : 25.6 MB
    char* p = (char*)d_ws;
    unsigned short* support = (unsigned short*)p;  p += (size_t)N * OUT_DIM * sizeof(unsigned short);
    __bf16* Wt      = (__bf16*)p;           p += (size_t)IN_DIM * OUT_DIM * sizeof(__bf16);
    int*    counts  = (int*)p;              p += (size_t)N * sizeof(int);
    int*    base    = (int*)p;              p += (size_t)N * sizeof(int);
    int*    cursor  = (int*)p;              p += (size_t)N * sizeof(int);
    int*    gcursor = (int*)p;              p += 16;
    unsigned long long* sorted = (unsigned long long*)p;  p += (size_t)E * sizeof(unsigned long long);

    convert_weight<<<(IN_DIM * OUT_DIM) / 256, 256, 0, stream>>>(W, Wt);

    const int row_tiles   = (N + 15) / 16;
    const int gemm_blocks = (row_tiles + 3) / 4;
    gemm_tanh<<<gemm_blocks, 256, 0, stream>>>(x, Wt, (__hip_bfloat16*)support, activ, N);

    hipMemsetAsync(counts, 0, (size_t)N * sizeof(int), stream);
    hipMemsetAsync(gcursor, 0, 16, stream);

    const int eblocks = (E + 255) / 256;
    edge_hist<<<eblocks, 256, 0, stream>>>(erows, counts, E);
    alloc_bases<<<(N + 255) / 256, 256, 0, stream>>>(counts, base, cursor, gcursor, N);
    edge_scatter<<<eblocks, 256, 0, stream>>>(erows, ecols, evals, cursor, sorted, E);

    const int acc_blocks = (N + 3) / 4;    // wave per row, 4 waves/block
    row_accumulate<<<acc_blocks, 256, 0, stream>>>(support, base, counts, sorted, out, N);
}

// Round 4
// 997.029 us; speedup vs baseline: 11.1082x; 1.1621x over previous
//
#include <hip/hip_runtime.h>
#include <hip/hip_bf16.h>

// Problem constants (from reference): N=100000, IN=512, OUT=256, E=3200000
#define IN_DIM  512
#define OUT_DIM 256

using bf16x8 = __attribute__((ext_vector_type(8))) __bf16;
using f32x4  = __attribute__((ext_vector_type(4))) float;

__device__ __forceinline__ void async_lds16(const void* g, void* l) {
    __builtin_amdgcn_global_load_lds(
        (const __attribute__((address_space(1))) void*)g,
        (__attribute__((address_space(3))) void*)l, 16, 0, 0);
}

// --- Kernel 1: W[512][256] f32 -> Wt[256][512] bf16 (transposed, for B-frag rows) ---
__global__ void convert_weight(const float* __restrict__ W, __bf16* __restrict__ Wt) {
    int idx = blockIdx.x * blockDim.x + threadIdx.x;   // 0..131071
    int n = idx >> 9;          // out col
    int k = idx & 511;         // in dim
    Wt[idx] = (__bf16)W[k * OUT_DIM + n];
}

// --- Kernel 2: support = tanh(x @ W) in bf16 ---
// Block = 256 thr (4 waves) = 64-row tile x 256 cols. Wt k-slices staged to LDS
// (16 KB per k0 of 32, double-buffered, global_load_lds w=16, m97 structure).
__launch_bounds__(256)
__global__ void gemm_tanh(const float* __restrict__ x, const __bf16* __restrict__ Wt,
                          __hip_bfloat16* __restrict__ support, const int* __restrict__ active,
                          int N) {
    __shared__ __bf16 Bt[2][256 * 32];   // [buf][n][32 k] bf16, row = 64 B

    const int tid  = threadIdx.x;
    const int wave = tid >> 6;
    const int lane = tid & 63;
    const int m    = lane & 15;     // A row / B col / C col
    const int quad = lane >> 4;     // k-block selector, C row-block

    int r0 = blockIdx.x * 64 + wave * 16;
    if (r0 + 16 > N) r0 = N - 16;   // clamp (duplicate work, identical values; keeps barriers uniform)

    const float* xrow = x + (size_t)(r0 + m) * IN_DIM;

    // Staging addressing: idx = j*256 + tid; n = idx>>2, kp = idx&3
    // global byte addr = n*1024 + k0*2 + kp*16 ; LDS dest = buf + idx*16 (lane-ordered)
    const char* WtB = (const char*)Wt;

    f32x4 acc[16];
#pragma unroll
    for (int t = 0; t < 16; ++t) acc[t] = (f32x4)0.0f;

    // prefetch k-slice 0 into buf 0
    {
        const int k0 = 0;
#pragma unroll
        for (int j = 0; j < 4; ++j) {
            int idx = j * 256 + tid;
            int n = idx >> 2, kp = idx & 3;
            async_lds16(WtB + (size_t)n * 1024 + k0 * 2 + kp * 16,
                        (char*)&Bt[0][0] + ((j * 4 + wave) * 64 + lane) * 16);
        }
    }

    int cur = 0;
    for (int kk = 0; kk < 16; ++kk) {
        __syncthreads();   // drains vmcnt -> Bt[cur] ready
        if (kk + 1 < 16) {
            const int k0n = (kk + 1) * 32;
#pragma unroll
            for (int j = 0; j < 4; ++j) {
                int idx = j * 256 + tid;
                int n = idx >> 2, kp = idx & 3;
                async_lds16(WtB + (size_t)n * 1024 + k0n * 2 + kp * 16,
                            (char*)&Bt[cur ^ 1][0] + ((j * 4 + wave) * 64 + lane) * 16);
            }
        }

        // A fragment: x[r0+m][kk*32 + quad*8 + j], f32 -> bf16
        const float4* ap = (const float4*)(xrow + kk * 32 + quad * 8);
        float4 a0 = ap[0];
        float4 a1 = ap[1];
        bf16x8 af;
        af[0] = (__bf16)a0.x; af[1] = (__bf16)a0.y; af[2] = (__bf16)a0.z; af[3] = (__bf16)a0.w;
        af[4] = (__bf16)a1.x; af[5] = (__bf16)a1.y; af[6] = (__bf16)a1.z; af[7] = (__bf16)a1.w;

#pragma unroll
        for (int t = 0; t < 16; ++t) {
            // B fragment from LDS: n = t*16+m, k = quad*8..+8
            bf16x8 bf = *(const bf16x8*)&Bt[cur][(t * 16 + m) * 32 + quad * 8];
            acc[t] = __builtin_amdgcn_mfma_f32_16x16x32_bf16(af, bf, acc[t], 0, 0, 0);
        }
        cur ^= 1;
    }

    const int act = active[0];
    const int row_base = r0 + quad * 4;
#pragma unroll
    for (int t = 0; t < 16; ++t) {
#pragma unroll
        for (int r = 0; r < 4; ++r) {
            float v = acc[t][r];
            if (act) v = tanhf(v);
            support[(size_t)(row_base + r) * OUT_DIM + t * 16 + m] = __float2bfloat16(v);
        }
    }
}

// --- Kernel 3a: histogram of destination rows ---
__launch_bounds__(256)
__global__ void edge_hist(const int* __restrict__ rows, int* __restrict__ counts, int E) {
    int e = blockIdx.x * 256 + threadIdx.x;
    if (e < E) atomicAdd(&counts[rows[e]], 1);
}

// --- Kernel 3b: allocate contiguous segment bases (wave prefix-sum + 1 atomic/wave) ---
__launch_bounds__(256)
__global__ void alloc_bases(const int* __restrict__ counts, int* __restrict__ base,
                            int* __restrict__ cursor, int* __restrict__ gcursor, int N) {
    int i = blockIdx.x * 256 + threadIdx.x;
    int lane = threadIdx.x & 63;
    int c = (i < N) ? counts[i] : 0;
    int pref = c;
#pragma unroll
    for (int d = 1; d < 64; d <<= 1) {
        int up = __shfl_up(pref, d, 64);
        if (lane >= d) pref += up;
    }
    int total = __shfl(pref, 63, 64);
    int waveBase = 0;
    if (lane == 63) waveBase = atomicAdd(gcursor, total);
    waveBase = __shfl(waveBase, 63, 64);
    int b = waveBase + pref - c;
    if (i < N) { base[i] = b; cursor[i] = b; }
}

// --- Kernel 3c: scatter (col, val) into row-contiguous segments ---
// Plain stores (NOT non-temporal): consecutive edges of a segment merge in L2
// before writeback — nt stores caused 8x write amplification (R3: 200 MB for 25.6 MB).
__launch_bounds__(256)
__global__ void edge_scatter(const int* __restrict__ rows, const int* __restrict__ cols,
                             const float* __restrict__ vals, int* __restrict__ cursor,
                             unsigned long long* __restrict__ sorted, int E) {
    int e = blockIdx.x * 256 + threadIdx.x;
    if (e >= E) return;
    int r = rows[e];
    int pos = atomicAdd(&cursor[r], 1);
    unsigned long long packed = (unsigned int)cols[e] |
        ((unsigned long long)(unsigned int)__float_as_int(vals[e]) << 32);
    sorted[pos] = packed;
}

// --- Kernel 3d: one wave per output row; register-accumulate its edge segment ---
__launch_bounds__(256)
__global__ void row_accumulate(const unsigned short* __restrict__ support,
                               const int* __restrict__ base,
                               const int* __restrict__ counts,
                               const unsigned long long* __restrict__ sorted,
                               float* __restrict__ out, int N) {
    int w    = (int)((blockIdx.x * 256u + threadIdx.x) >> 6);  // row id
    int lane = threadIdx.x & 63;
    if (w >= N) return;
    int e   = base[w];
    int end = e + counts[w];

    float a0 = 0.f, a1 = 0.f, a2 = 0.f, a3 = 0.f;

    for (; e + 4 <= end; e += 4) {
        unsigned long long p0 = __builtin_nontemporal_load(&sorted[e]);
        unsigned long long p1 = __builtin_nontemporal_load(&sorted[e + 1]);
        unsigned long long p2 = __builtin_nontemporal_load(&sorted[e + 2]);
        unsigned long long p3 = __builtin_nontemporal_load(&sorted[e + 3]);
#pragma unroll
        for (int j = 0; j < 4; ++j) {
            unsigned long long p = (j == 0) ? p0 : (j == 1) ? p1 : (j == 2) ? p2 : p3;
            int   c = (int)(unsigned int)p;
            float v = __int_as_float((int)(p >> 32));
            uint2 u = *((const uint2*)(support + (size_t)c * OUT_DIM) + lane);
            a0 = fmaf(v, __uint_as_float(u.x << 16),          a0);
            a1 = fmaf(v, __uint_as_float(u.x & 0xffff0000u),  a1);
            a2 = fmaf(v, __uint_as_float(u.y << 16),          a2);
            a3 = fmaf(v, __uint_as_float(u.y & 0xffff0000u),  a3);
        }
    }
    for (; e < end; ++e) {
        unsigned long long p = __builtin_nontemporal_load(&sorted[e]);
        int   c = (int)(unsigned int)p;
        float v = __int_as_float((int)(p >> 32));
        uint2 u = *((const uint2*)(support + (size_t)c * OUT_DIM) + lane);
        a0 = fmaf(v, __uint_as_float(u.x << 16),          a0);
        a1 = fmaf(v, __uint_as_float(u.x & 0xffff0000u),  a1);
        a2 = fmaf(v, __uint_as_float(u.y << 16),          a2);
        a3 = fmaf(v, __uint_as_float(u.y & 0xffff0000u),  a3);
    }
    float4 o;
    o.x = a0; o.y = a1; o.z = a2; o.w = a3;
    *((float4*)(out + (size_t)w * OUT_DIM) + lane) = o;
}

extern "C" void kernel_launch(void* const* d_in, const int* in_sizes, int n_in,
                              void* d_out, int out_size, void* d_ws, size_t ws_size,
                              hipStream_t stream) {
    const float* x     = (const float*)d_in[0];
    const float* W     = (const float*)d_in[1];
    const int*   erows = (const int*)d_in[2];
    const int*   ecols = (const int*)d_in[3];
    const float* evals = (const float*)d_in[4];
    const int*   activ = (const int*)d_in[5];
    float*       out   = (float*)d_out;

    const int N = in_sizes[0] / IN_DIM;   // 100000
    const int E = in_sizes[2];            // 3200000

    // Workspace layout:
    //   support bf16 [N][256] | Wt bf16 [256][512] | counts/base/cursor int [N]
    //   gcursor int[4] | sorted u64 [E]
    char* p = (char*)d_ws;
    unsigned short* support = (unsigned short*)p;  p += (size_t)N * OUT_DIM * sizeof(unsigned short);
    __bf16* Wt      = (__bf16*)p;           p += (size_t)IN_DIM * OUT_DIM * sizeof(__bf16);
    int*    counts  = (int*)p;              p += (size_t)N * sizeof(int);
    int*    base    = (int*)p;              p += (size_t)N * sizeof(int);
    int*    cursor  = (int*)p;              p += (size_t)N * sizeof(int);
    int*    gcursor = (int*)p;              p += 16;
    unsigned long long* sorted = (unsigned long long*)p;  p += (size_t)E * sizeof(unsigned long long);

    convert_weight<<<(IN_DIM * OUT_DIM) / 256, 256, 0, stream>>>(W, Wt);

    const int gemm_blocks = (N + 63) / 64;   // 1563
    gemm_tanh<<<gemm_blocks, 256, 0, stream>>>(x, Wt, (__hip_bfloat16*)support, activ, N);

    hipMemsetAsync(counts, 0, (size_t)N * sizeof(int), stream);
    hipMemsetAsync(gcursor, 0, 16, stream);

    const int eblocks = (E + 255) / 256;
    edge_hist<<<eblocks, 256, 0, stream>>>(erows, counts, E);
    alloc_bases<<<(N + 255) / 256, 256, 0, stream>>>(counts, base, cursor, gcursor, N);
    edge_scatter<<<eblocks, 256, 0, stream>>>(erows, ecols, evals, cursor, sorted, E);

    const int acc_blocks = (N + 3) / 4;    // wave per row, 4 waves/block
    row_accumulate<<<acc_blocks, 256, 0, stream>>>(support, base, counts, sorted, out, N);
}